// Round 15
// baseline (232.913 us; speedup 1.0000x reference)
//
#include <hip/hip_runtime.h>
#include <float.h>
#include <math.h>

#define NBATCH   4096
#define NAGENT   16
#define NTASK    16
#define DDIM     128
#define G        8      // batches per block (one per wave)
#define NTHREADS 512    // 8 waves; halves of 4 waves each for phase M
#define SSEG     20     // scr segment stride (16 data + 4 pad dwords)

typedef float f32x2 __attribute__((ext_vector_type(2)));

// DPP lane permutes (VALU pipe, bits 0-3 only):
//   0xB1 quad_perm xor1, 0x4E quad_perm xor2,
//   0x141 row_half_mirror = xor7, 0x140 row_mirror = xor15
template<int CTRL>
__device__ __forceinline__ float dppf(float x) {
    return __int_as_float(__builtin_amdgcn_update_dpp(
        0, __float_as_int(x), CTRL, 0xF, 0xF, true));
}
template<int CTRL>
__device__ __forceinline__ int dppi(int x) {
    return __builtin_amdgcn_update_dpp(0, x, CTRL, 0xF, 0xF, true);
}

// packed fp32 fma: acc.{lo,hi} += bcast(a.{lo|hi per SEL}) * b.{lo,hi}
template<int SEL>
__device__ __forceinline__ void pk_fma_b(f32x2& acc, f32x2 a, f32x2 b) {
    if constexpr (SEL == 0)
        asm("v_pk_fma_f32 %0, %1, %2, %0 op_sel:[0,0,0] op_sel_hi:[0,1,1]"
            : "+v"(acc) : "v"(a), "v"(b));
    else
        asm("v_pk_fma_f32 %0, %1, %2, %0 op_sel:[1,0,0] op_sel_hi:[1,1,1]"
            : "+v"(acc) : "v"(a), "v"(b));
}

// 3-op packed merge over a DPP lane-xor level (own-half-first order; r13/r14
// proven absmax 0.0).
template<int CTRL>
__device__ __forceinline__ float merge_dpp(float lo, float hi, bool h) {
    const float a = lo + dppf<CTRL>(lo);
    const float b = hi + dppf<CTRL>(hi);
    return h ? b : a;
}

// Lane-order permuted W for the 256-htid half-block mapping
// (iseg=htid&15, cg8=htid>>4): wp[(c*8 + di*2 + hc)*256 + htid] =
//   W_upd[(htid&15)*16 + c*4 + di][(htid>>4)*8 + hc*4 .. +3]
__global__ void wperm_kernel(const float* __restrict__ W_upd,
                             float4* __restrict__ wp) {
    const int q  = blockIdx.x * 256 + threadIdx.x;   // 0..8191
    const int t  = q & 255;
    const int rh = q >> 8;            // 0..31: bit0=hc, bits1-2=di, bits3-4=c
    const int hc = rh & 1;
    const int di = (rh >> 1) & 3;
    const int c  = rh >> 3;
    const int i  = (t & 15) * 16 + c * 4 + di;
    const int col = (t >> 4) * 8 + hc * 4;
    wp[q] = *(const float4*)(W_upd + (size_t)i * DDIM + col);
}

// VGPR-POOL LAW (r2..r13): waves/SIMD = floor(256/VGPR); min=4 -> 64-reg cap,
// 16 waves/CU (39% occ, r11/r12/r14). DS pipe is the binding resource (r14):
// this version halves the matvec scr reads (C=8 half-block tiling) and moves
// softmax reduces to mirror-DPPs (VALU).
template<bool PERM>
__global__ __launch_bounds__(NTHREADS)
__attribute__((amdgpu_waves_per_eu(4, 8)))
void alloc_policy_kernel(const float* __restrict__ task_embeds,
                         const float* __restrict__ task_nonag,
                         const float* __restrict__ agent_embeds,
                         const unsigned char* __restrict__ task_mask,
                         const float* __restrict__ agent_mask,
                         const float* __restrict__ gumbels,
                         const float* __restrict__ W_count,
                         const float* __restrict__ b_count,
                         const float* __restrict__ W_upd,
                         const float* __restrict__ b_upd,
                         const float4* __restrict__ wperm,
                         float* __restrict__ out)
{
    __shared__ __align__(16) float te[G][NTASK][DDIM];     // 64 KB
    __shared__ __align__(16) float scr[G][16 * SSEG];      // 10 KB
    __shared__ __align__(16) float4 sdots4[G][NAGENT];     // 2 KB
    __shared__ __align__(16) float4 upd4[G];

    const int tid  = threadIdx.x;
    const int lane = tid & 63;
    const int w    = tid >> 6;
    const int b0   = blockIdx.x * G;
    const int gb_w = b0 + w;

    const bool h0 = (lane & 1) != 0;
    const bool h1 = (lane & 2) != 0;
    const bool h2 = (lane & 4) != 0;
    const bool h3 = (lane & 8) != 0;

    // phase-M half-block mapping: halfid owns batches 4*halfid..+3;
    // cg8 owns cols cg8*8..+7; iseg owns i in [iseg*16, +16)
    const int halfid = tid >> 8;          // 0 or 1
    const int htid   = tid & 255;
    const int iseg   = htid & 15;         // == lane & 15
    const int cg8    = htid >> 4;         // 0..15
    const float bu = b_upd[cg8 * 8 + (lane & 7)];

    const float scalef = sqrtf(128.0f);

    // ---- init te
    {
        const float4* src = (const float4*)(task_embeds + (size_t)b0 * NTASK * DDIM);
        float4* dst = (float4*)(&te[0][0][0]);
        #pragma unroll
        for (int k = 0; k < (G * NTASK * DDIM / 4) / NTHREADS; ++k)  // 8
            dst[k * NTHREADS + tid] = src[k * NTHREADS + tid];
    }

    // ---- init sdots4 per (g,a): s0=dot(ag,Wc0), s1=dot(ag,Wc1), s2=dot(ag,bc)
    {
        const int p = tid >> 2, q = tid & 3;
        const int g = p >> 4,  a = p & 15;
        const float* agp = agent_embeds + ((size_t)(b0 + g) * NAGENT + a) * DDIM + q * 32;
        float a0 = 0.f, a1 = 0.f, a2 = 0.f;
        #pragma unroll
        for (int c = 0; c < 8; ++c) {
            const float4 av = *(const float4*)(agp + c * 4);
            const float4 w0 = *(const float4*)(W_count + q * 32 + c * 4);
            const float4 w1 = *(const float4*)(W_count + DDIM + q * 32 + c * 4);
            const float4 bc = *(const float4*)(b_count + q * 32 + c * 4);
            a0 = fmaf(av.x, w0.x, a0); a0 = fmaf(av.y, w0.y, a0);
            a0 = fmaf(av.z, w0.z, a0); a0 = fmaf(av.w, w0.w, a0);
            a1 = fmaf(av.x, w1.x, a1); a1 = fmaf(av.y, w1.y, a1);
            a1 = fmaf(av.z, w1.z, a1); a1 = fmaf(av.w, w1.w, a1);
            a2 = fmaf(av.x, bc.x, a2); a2 = fmaf(av.y, bc.y, a2);
            a2 = fmaf(av.z, bc.z, a2); a2 = fmaf(av.w, bc.w, a2);
        }
        a0 += __shfl_xor(a0, 1); a0 += __shfl_xor(a0, 2);
        a1 += __shfl_xor(a1, 1); a1 += __shfl_xor(a1, 2);
        a2 += __shfl_xor(a2, 1); a2 += __shfl_xor(a2, 2);
        if (q == 0) sdots4[g][a] = make_float4(a0, a1, a2, 0.f);
    }

    const int tau = lane & 15;
    const float nn_my = task_nonag[gb_w * NTASK + tau];
    const unsigned char mask_my = task_mask[gb_w * NTASK + tau];
    float cc_my = 0.0f;

    const float* agbase = agent_embeds + (size_t)gb_w * NAGENT * DDIM;
    float2 ag2 = *(const float2*)(agbase + lane * 2);                // a=0
    float  gum = gumbels[(size_t)gb_w * NTASK + tau];                // a=0
    float  amk = agent_mask[(size_t)gb_w * NAGENT + 0];

    __syncthreads();

    for (int a = 0; a < NAGENT; ++a) {
        // ================= phase L (wave-private, bit-identical to r14) ======
        float v[16];
        #pragma unroll
        for (int t = 0; t < 16; ++t) {
            const float2 t2 = *(const float2*)(&te[w][t][lane * 2]);
            v[t] = fmaf(ag2.y, t2.y, ag2.x * t2.x);
        }
        float p8[8];
        #pragma unroll
        for (int m2 = 0; m2 < 8; ++m2)
            p8[m2] = merge_dpp<0xB1>(v[2 * m2], v[2 * m2 + 1], h0);
        float p4[4];
        #pragma unroll
        for (int m2 = 0; m2 < 4; ++m2)
            p4[m2] = merge_dpp<0x4E>(p8[2 * m2], p8[2 * m2 + 1], h1);
        float p2v[2];
        #pragma unroll
        for (int m2 = 0; m2 < 2; ++m2) {
            const float lo = p2v[m2] = 0.f, hi = 0.f;  // placeholders (overwritten)
            (void)lo; (void)hi;
        }
        #pragma unroll
        for (int m2 = 0; m2 < 2; ++m2) {
            const float lo = p4[2 * m2], hi = p4[2 * m2 + 1];
            const float send = h2 ? lo : hi;
            const float mine = h2 ? hi : lo;
            p2v[m2] = mine + __shfl_xor(send, 4);
        }
        float p1;
        {
            const float lo = p2v[0], hi = p2v[1];
            const float send = h3 ? lo : hi;
            const float mine = h3 ? hi : lo;
            p1 = mine + __shfl_xor(send, 8);
        }
        p1 += __shfl_xor(p1, 16);
        p1 += __shfl_xor(p1, 32);   // all 64 lanes: full dot(ag, te[tau])

        // ================= phase S: softmax/argmax via mirror-DPPs ==========
        const float4 sd = sdots4[w][a];
        const float dot_total = p1 + fmaf(nn_my, sd.x, fmaf(cc_my, sd.y, sd.z));
        float z = dot_total / scalef;
        if (mask_my) z = -FLT_MAX;
        z = z + gum;

        // masks {1,2,7,15} span lane bits 0-3; max/min exact, sum ulp-reroll
        float mz = z;
        mz = fmaxf(mz, dppf<0xB1>(mz));
        mz = fmaxf(mz, dppf<0x4E>(mz));
        mz = fmaxf(mz, dppf<0x141>(mz));
        mz = fmaxf(mz, dppf<0x140>(mz));
        const float e = expf(z - mz);
        float ss = e;
        ss += dppf<0xB1>(ss);
        ss += dppf<0x4E>(ss);
        ss += dppf<0x141>(ss);
        ss += dppf<0x140>(ss);
        const float sft = e / ss;

        float mx = sft;
        mx = fmaxf(mx, dppf<0xB1>(mx));
        mx = fmaxf(mx, dppf<0x4E>(mx));
        mx = fmaxf(mx, dppf<0x141>(mx));
        mx = fmaxf(mx, dppf<0x140>(mx));
        int cand = (sft == mx) ? tau : NTASK;
        cand = min(cand, dppi<0xB1>(cand));
        cand = min(cand, dppi<0x4E>(cand));
        cand = min(cand, dppi<0x141>(cand));
        cand = min(cand, dppi<0x140>(cand));
        const int bi = cand;

        const float agm = 1.0f - amk;
        const float onehot = (tau == bi) ? 1.0f : 0.0f;
        const float hh = ((onehot - sft) + sft) * agm;   // exact 0 / exact agm

        if (lane < 16)
            out[((size_t)gb_w * NAGENT + a) * NTASK + tau] = hh;
        cc_my = cc_my + hh * 0.1f;
        if (lane < 16 && tau == bi)
            upd4[w] = make_float4(__int_as_float(bi), hh, agm, 0.f);

        // stage relu(concat(te[bi], ag)) into seg-strided scratch
        {
            const float2 tsel = *(const float2*)(&te[w][bi][lane * 2]);
            float2 r0, r1;
            r0.x = fmaxf(tsel.x, 0.f); r0.y = fmaxf(tsel.y, 0.f);
            r1.x = fmaxf(ag2.x, 0.f);  r1.y = fmaxf(ag2.y, 0.f);
            const int i0 = 2 * lane;
            const int i1 = 128 + 2 * lane;
            *(float2*)(&scr[w][(i0 >> 4) * SSEG + (i0 & 15)]) = r0;
            *(float2*)(&scr[w][(i1 >> 4) * SSEG + (i1 & 15)]) = r1;
        }

        // prefetch next step's globals (latency hidden under phase M)
        const int an = (a + 1) & 15;
        const float2 ag2n = *(const float2*)(agbase + (size_t)an * DDIM + lane * 2);
        const float  gumn = gumbels[((size_t)an * NBATCH + gb_w) * NTASK + tau];
        const float  amkn = agent_mask[(size_t)gb_w * NAGENT + an];

        __syncthreads();   // barrier 1: scr + upd4 published

        // ===== phase M: half-block C=8 matvec (4 batches per half) ==========
        // accP[g*4+p] = cols (2p, 2p+1) of batch 4*halfid+g
        f32x2 accP[16];
        #pragma unroll
        for (int j = 0; j < 16; ++j) accP[j] = f32x2{0.f, 0.f};
        #pragma unroll
        for (int c = 0; c < 4; ++c) {
            const int sb = iseg * SSEG + c * 4;
            float4 in4[4];
            #pragma unroll
            for (int g = 0; g < 4; ++g)
                in4[g] = *(const float4*)(&scr[halfid * 4 + g][sb]);
            #pragma unroll
            for (int hc = 0; hc < 2; ++hc) {
                float4 W0, W1, W2, W3;   // rows di=0..3, cols cg8*8+hc*4..+3
                if (PERM) {
                    const float4* wp = wperm + (size_t)(c * 8 + hc) * 256 + htid;
                    W0 = wp[0 * 256];
                    W1 = wp[2 * 256];
                    W2 = wp[4 * 256];
                    W3 = wp[6 * 256];
                } else {
                    const float* wrow = W_upd +
                        (size_t)(iseg * 16 + c * 4) * DDIM + cg8 * 8 + hc * 4;
                    W0 = *(const float4*)(wrow + 0 * DDIM);
                    W1 = *(const float4*)(wrow + 1 * DDIM);
                    W2 = *(const float4*)(wrow + 2 * DDIM);
                    W3 = *(const float4*)(wrow + 3 * DDIM);
                }
                const f32x2 wA0 = f32x2{W0.x, W0.y}, wB0 = f32x2{W0.z, W0.w};
                const f32x2 wA1 = f32x2{W1.x, W1.y}, wB1 = f32x2{W1.z, W1.w};
                const f32x2 wA2 = f32x2{W2.x, W2.y}, wB2 = f32x2{W2.z, W2.w};
                const f32x2 wA3 = f32x2{W3.x, W3.y}, wB3 = f32x2{W3.z, W3.w};
                #pragma unroll
                for (int g = 0; g < 4; ++g) {
                    const f32x2 ixy = f32x2{in4[g].x, in4[g].y};
                    const f32x2 izw = f32x2{in4[g].z, in4[g].w};
                    f32x2& aA = accP[g * 4 + hc * 2];
                    f32x2& aB = accP[g * 4 + hc * 2 + 1];
                    pk_fma_b<0>(aA, ixy, wA0);   // i = c*4+0
                    pk_fma_b<1>(aA, ixy, wA1);   // i = c*4+1
                    pk_fma_b<0>(aA, izw, wA2);   // i = c*4+2
                    pk_fma_b<1>(aA, izw, wA3);   // i = c*4+3
                    pk_fma_b<0>(aB, ixy, wB0);
                    pk_fma_b<1>(aB, ixy, wB1);
                    pk_fma_b<0>(aB, izw, wB2);
                    pk_fma_b<1>(aB, izw, wB3);
                }
            }
        }
        // packed reduce over iseg lanes (bits 0..3), same tree as r14
        float q16[16];
        #pragma unroll
        for (int m2 = 0; m2 < 16; ++m2)
            q16[m2] = merge_dpp<0xB1>(accP[m2].x, accP[m2].y, h0);
        float q8[8];
        #pragma unroll
        for (int m2 = 0; m2 < 8; ++m2)
            q8[m2] = merge_dpp<0x4E>(q16[2 * m2], q16[2 * m2 + 1], h1);
        float q4[4];
        #pragma unroll
        for (int m2 = 0; m2 < 4; ++m2) {
            const float lo = q8[2 * m2], hi = q8[2 * m2 + 1];
            const float send = h2 ? lo : hi;
            const float mine = h2 ? hi : lo;
            q4[m2] = mine + __shfl_xor(send, 4);
        }
        float q2[2];
        #pragma unroll
        for (int m2 = 0; m2 < 2; ++m2) {
            const float lo = q4[2 * m2], hi = q4[2 * m2 + 1];
            const float send = h3 ? lo : hi;
            const float mine = h3 ? hi : lo;
            q2[m2] = mine + __shfl_xor(send, 8);
        }
        // epilogue: lane holds j = 16*hgi + (lane&15); j = g_local*8 + (lane&7)
        //   -> g = ((lane>>3)&1) + 2*hgi + 4*halfid, col = cg8*8 + (lane&7)
        #pragma unroll
        for (int hgi = 0; hgi < 2; ++hgi) {
            const int g = ((lane >> 3) & 1) + 2 * hgi + 4 * halfid;
            const float4 u4 = upd4[g];
            const int ts = __float_as_int(u4.x);
            const float u = q2[hgi] + bu;
            const float addv = (u * u4.y) * u4.z;
            te[g][ts][cg8 * 8 + (lane & 7)] += addv;
        }
        __syncthreads();   // barrier 2: te fully updated

        ag2 = ag2n; gum = gumn; amk = amkn;
    }
}

extern "C" void kernel_launch(void* const* d_in, const int* in_sizes, int n_in,
                              void* d_out, int out_size, void* d_ws, size_t ws_size,
                              hipStream_t stream) {
    const float*         task_embeds  = (const float*)d_in[0];
    const float*         task_nonag   = (const float*)d_in[1];
    const float*         agent_embeds = (const float*)d_in[2];
    const unsigned char* task_mask    = (const unsigned char*)d_in[3];
    const float*         agent_mask   = (const float*)d_in[4];
    const float*         gumbels      = (const float*)d_in[5];
    const float*         W_count      = (const float*)d_in[6];
    const float*         b_count      = (const float*)d_in[7];
    const float*         W_upd        = (const float*)d_in[8];
    const float*         b_upd        = (const float*)d_in[9];
    float* out = (float*)d_out;

    dim3 grid(NBATCH / G);
    dim3 block(NTHREADS);

    if (ws_size >= 2 * DDIM * DDIM * sizeof(float)) {   // 128 KB for wperm
        float4* wp = (float4*)d_ws;
        hipLaunchKernelGGL(wperm_kernel, dim3(32), dim3(256), 0, stream, W_upd, wp);
        hipLaunchKernelGGL(alloc_policy_kernel<true>, grid, block, 0, stream,
                           task_embeds, task_nonag, agent_embeds, task_mask,
                           agent_mask, gumbels, W_count, b_count, W_upd, b_upd,
                           wp, out);
    } else {
        hipLaunchKernelGGL(alloc_policy_kernel<false>, grid, block, 0, stream,
                           task_embeds, task_nonag, agent_embeds, task_mask,
                           agent_mask, gumbels, W_count, b_count, W_upd, b_upd,
                           (const float4*)nullptr, out);
    }
}

// Round 16
// 134.690 us; speedup vs baseline: 1.7293x; 1.7293x over previous
//
#include <hip/hip_runtime.h>
#include <float.h>
#include <math.h>

#define NBATCH   4096
#define NAGENT   16
#define NTASK    16
#define DDIM     128
#define G        4      // batches per block (one per wave)
#define NTHREADS 256    // 4 waves; 3 blocks/CU target
#define SSEG     20     // scr segment stride (16 data + 4 pad dwords)

typedef float f32x2 __attribute__((ext_vector_type(2)));

// DPP lane permutes (VALU pipe, lane bits 0-3):
//   0xB1 quad_perm xor1, 0x4E quad_perm xor2,
//   0x141 row_half_mirror = xor7, 0x140 row_mirror = xor15
template<int CTRL>
__device__ __forceinline__ float dppf(float x) {
    return __int_as_float(__builtin_amdgcn_update_dpp(
        0, __float_as_int(x), CTRL, 0xF, 0xF, true));
}
template<int CTRL>
__device__ __forceinline__ int dppi(int x) {
    return __builtin_amdgcn_update_dpp(0, x, CTRL, 0xF, 0xF, true);
}

// packed fp32 fma: acc.{lo,hi} += bcast(a.{lo|hi per SEL}) * b.{lo,hi}
template<int SEL>
__device__ __forceinline__ void pk_fma_b(f32x2& acc, f32x2 a, f32x2 b) {
    if constexpr (SEL == 0)
        asm("v_pk_fma_f32 %0, %1, %2, %0 op_sel:[0,0,0] op_sel_hi:[0,1,1]"
            : "+v"(acc) : "v"(a), "v"(b));
    else
        asm("v_pk_fma_f32 %0, %1, %2, %0 op_sel:[1,0,0] op_sel_hi:[1,1,1]"
            : "+v"(acc) : "v"(a), "v"(b));
}

// 3-op packed merge over a DPP lane-xor level (own-half-first order;
// r13/r14/r15 proven absmax 0.0)
template<int CTRL>
__device__ __forceinline__ float merge_dpp(float lo, float hi, bool h) {
    const float a = lo + dppf<CTRL>(lo);
    const float b = hi + dppf<CTRL>(hi);
    return h ? b : a;
}

// Lane-order permuted W for the 256-thread mapping (iseg=tid&15, cg8=tid>>4):
// wp[(c*8 + di*2 + hc)*256 + tid] =
//   W_upd[(tid&15)*16 + c*4 + di][(tid>>4)*8 + hc*4 .. +3]
__global__ void wperm_kernel(const float* __restrict__ W_upd,
                             float4* __restrict__ wp) {
    const int q  = blockIdx.x * 256 + threadIdx.x;   // 0..8191
    const int t  = q & 255;
    const int rh = q >> 8;            // 0..31: bit0=hc, bits1-2=di, bits3-4=c
    const int hc = rh & 1;
    const int di = (rh >> 1) & 3;
    const int c  = rh >> 3;
    const int i  = (t & 15) * 16 + c * 4 + di;
    const int col = (t >> 4) * 8 + hc * 4;
    wp[q] = *(const float4*)(W_upd + (size_t)i * DDIM + col);
}

// VGPR-POOL LAW (r2..r15): waves/SIMD = floor(256/VGPR); waves_per_eu MIN
// sets the allocator cap at 256/min. C=8 matvec needs ~70 live regs ->
// incompatible with the 64-cap (r15 spilled). min=3 -> cap 85; 256-thread
// blocks -> 3 blocks/CU = 12 waves/CU; LDS 38.4KB x3 = 115KB fits.
template<bool PERM>
__global__ __launch_bounds__(NTHREADS)
__attribute__((amdgpu_waves_per_eu(3, 8)))
void alloc_policy_kernel(const float* __restrict__ task_embeds,
                         const float* __restrict__ task_nonag,
                         const float* __restrict__ agent_embeds,
                         const unsigned char* __restrict__ task_mask,
                         const float* __restrict__ agent_mask,
                         const float* __restrict__ gumbels,
                         const float* __restrict__ W_count,
                         const float* __restrict__ b_count,
                         const float* __restrict__ W_upd,
                         const float* __restrict__ b_upd,
                         const float4* __restrict__ wperm,
                         float* __restrict__ out)
{
    __shared__ __align__(16) float te[G][NTASK][DDIM];     // 32 KB
    __shared__ __align__(16) float scr[G][16 * SSEG];      // 5 KB
    __shared__ __align__(16) float4 sdots4[G][NAGENT];     // 1 KB
    __shared__ __align__(16) float4 upd4[G];

    const int tid  = threadIdx.x;
    const int lane = tid & 63;
    const int w    = tid >> 6;            // wave id == batch slot g (0..3)
    const int b0   = blockIdx.x * G;
    const int gb_w = b0 + w;

    const bool h0 = (lane & 1) != 0;
    const bool h1 = (lane & 2) != 0;
    const bool h2 = (lane & 4) != 0;
    const bool h3 = (lane & 8) != 0;

    // phase-M mapping: cg8 owns cols cg8*8..+7; iseg owns i in [iseg*16, +16)
    const int iseg = tid & 15;            // == lane & 15
    const int cg8  = tid >> 4;            // 0..15
    const float bu = b_upd[cg8 * 8 + (lane & 7)];

    const float scalef = sqrtf(128.0f);

    // ---- init te (block-wide coalesced copy)
    {
        const float4* src = (const float4*)(task_embeds + (size_t)b0 * NTASK * DDIM);
        float4* dst = (float4*)(&te[0][0][0]);
        #pragma unroll
        for (int k = 0; k < (G * NTASK * DDIM / 4) / NTHREADS; ++k)  // 8
            dst[k * NTHREADS + tid] = src[k * NTHREADS + tid];
    }

    // ---- init sdots4 per (g,a): s0=dot(ag,Wc0), s1=dot(ag,Wc1), s2=dot(ag,bc)
    {
        const int p = tid >> 2, q = tid & 3;   // 64 (g,a) pairs x 4 quarters
        const int g = p >> 4,  a = p & 15;
        const float* agp = agent_embeds + ((size_t)(b0 + g) * NAGENT + a) * DDIM + q * 32;
        float a0 = 0.f, a1 = 0.f, a2 = 0.f;
        #pragma unroll
        for (int c = 0; c < 8; ++c) {
            const float4 av = *(const float4*)(agp + c * 4);
            const float4 w0 = *(const float4*)(W_count + q * 32 + c * 4);
            const float4 w1 = *(const float4*)(W_count + DDIM + q * 32 + c * 4);
            const float4 bc = *(const float4*)(b_count + q * 32 + c * 4);
            a0 = fmaf(av.x, w0.x, a0); a0 = fmaf(av.y, w0.y, a0);
            a0 = fmaf(av.z, w0.z, a0); a0 = fmaf(av.w, w0.w, a0);
            a1 = fmaf(av.x, w1.x, a1); a1 = fmaf(av.y, w1.y, a1);
            a1 = fmaf(av.z, w1.z, a1); a1 = fmaf(av.w, w1.w, a1);
            a2 = fmaf(av.x, bc.x, a2); a2 = fmaf(av.y, bc.y, a2);
            a2 = fmaf(av.z, bc.z, a2); a2 = fmaf(av.w, bc.w, a2);
        }
        a0 += __shfl_xor(a0, 1); a0 += __shfl_xor(a0, 2);
        a1 += __shfl_xor(a1, 1); a1 += __shfl_xor(a1, 2);
        a2 += __shfl_xor(a2, 1); a2 += __shfl_xor(a2, 2);
        if (q == 0) sdots4[g][a] = make_float4(a0, a1, a2, 0.f);
    }

    const int tau = lane & 15;
    const float nn_my = task_nonag[gb_w * NTASK + tau];
    const unsigned char mask_my = task_mask[gb_w * NTASK + tau];
    float cc_my = 0.0f;

    const float* agbase = agent_embeds + (size_t)gb_w * NAGENT * DDIM;
    float2 ag2 = *(const float2*)(agbase + lane * 2);                // a=0
    float  gum = gumbels[(size_t)gb_w * NTASK + tau];                // a=0
    float  amk = agent_mask[(size_t)gb_w * NAGENT + 0];

    __syncthreads();   // te + sdots4 ready

    for (int a = 0; a < NAGENT; ++a) {
        // ========== phase L: dots + packed merge tree (r14-bit-identical) ====
        float v[16];
        #pragma unroll
        for (int t = 0; t < 16; ++t) {
            const float2 t2 = *(const float2*)(&te[w][t][lane * 2]);
            v[t] = fmaf(ag2.y, t2.y, ag2.x * t2.x);
        }
        float p8[8];
        #pragma unroll
        for (int m2 = 0; m2 < 8; ++m2)
            p8[m2] = merge_dpp<0xB1>(v[2 * m2], v[2 * m2 + 1], h0);
        float p4[4];
        #pragma unroll
        for (int m2 = 0; m2 < 4; ++m2)
            p4[m2] = merge_dpp<0x4E>(p8[2 * m2], p8[2 * m2 + 1], h1);
        float p2v[2];
        #pragma unroll
        for (int m2 = 0; m2 < 2; ++m2) {
            const float lo = p4[2 * m2], hi = p4[2 * m2 + 1];
            const float send = h2 ? lo : hi;
            const float mine = h2 ? hi : lo;
            p2v[m2] = mine + __shfl_xor(send, 4);
        }
        float p1;
        {
            const float lo = p2v[0], hi = p2v[1];
            const float send = h3 ? lo : hi;
            const float mine = h3 ? hi : lo;
            p1 = mine + __shfl_xor(send, 8);
        }
        p1 += __shfl_xor(p1, 16);
        p1 += __shfl_xor(p1, 32);   // all 64 lanes: full dot(ag, te[tau])

        // ========== phase S: softmax/argmax via mirror-DPPs (r15-proven) =====
        const float4 sd = sdots4[w][a];
        const float dot_total = p1 + fmaf(nn_my, sd.x, fmaf(cc_my, sd.y, sd.z));
        float z = dot_total / scalef;
        if (mask_my) z = -FLT_MAX;
        z = z + gum;

        float mz = z;
        mz = fmaxf(mz, dppf<0xB1>(mz));
        mz = fmaxf(mz, dppf<0x4E>(mz));
        mz = fmaxf(mz, dppf<0x141>(mz));
        mz = fmaxf(mz, dppf<0x140>(mz));
        const float e = expf(z - mz);
        float ss = e;
        ss += dppf<0xB1>(ss);
        ss += dppf<0x4E>(ss);
        ss += dppf<0x141>(ss);
        ss += dppf<0x140>(ss);
        const float sft = e / ss;

        float mx = sft;
        mx = fmaxf(mx, dppf<0xB1>(mx));
        mx = fmaxf(mx, dppf<0x4E>(mx));
        mx = fmaxf(mx, dppf<0x141>(mx));
        mx = fmaxf(mx, dppf<0x140>(mx));
        int cand = (sft == mx) ? tau : NTASK;
        cand = min(cand, dppi<0xB1>(cand));
        cand = min(cand, dppi<0x4E>(cand));
        cand = min(cand, dppi<0x141>(cand));
        cand = min(cand, dppi<0x140>(cand));
        const int bi = cand;

        const float agm = 1.0f - amk;
        const float onehot = (tau == bi) ? 1.0f : 0.0f;
        const float hh = ((onehot - sft) + sft) * agm;   // exact 0 / exact agm

        if (lane < 16)
            out[((size_t)gb_w * NAGENT + a) * NTASK + tau] = hh;
        cc_my = cc_my + hh * 0.1f;
        if (lane < 16 && tau == bi)
            upd4[w] = make_float4(__int_as_float(bi), hh, agm, 0.f);

        // stage relu(concat(te[bi], ag)) into seg-strided scratch
        {
            const float2 tsel = *(const float2*)(&te[w][bi][lane * 2]);
            float2 r0, r1;
            r0.x = fmaxf(tsel.x, 0.f); r0.y = fmaxf(tsel.y, 0.f);
            r1.x = fmaxf(ag2.x, 0.f);  r1.y = fmaxf(ag2.y, 0.f);
            const int i0 = 2 * lane;
            const int i1 = 128 + 2 * lane;
            *(float2*)(&scr[w][(i0 >> 4) * SSEG + (i0 & 15)]) = r0;
            *(float2*)(&scr[w][(i1 >> 4) * SSEG + (i1 & 15)]) = r1;
        }

        // prefetch next step's globals (latency hidden under phase M)
        const int an = (a + 1) & 15;
        const float2 ag2n = *(const float2*)(agbase + (size_t)an * DDIM + lane * 2);
        const float  gumn = gumbels[((size_t)an * NBATCH + gb_w) * NTASK + tau];
        const float  amkn = agent_mask[(size_t)gb_w * NAGENT + an];

        __syncthreads();   // barrier 1: scr + upd4 published

        // ===== phase M: C=8 matvec, all 4 batches, W streamed from wperm =====
        // accP[g*4+p] = cols (2p, 2p+1) of batch g; live set ~70 regs < 85 cap
        f32x2 accP[16];
        #pragma unroll
        for (int j = 0; j < 16; ++j) accP[j] = f32x2{0.f, 0.f};
        #pragma unroll
        for (int c = 0; c < 4; ++c) {
            const int sb = iseg * SSEG + c * 4;
            float4 in4[4];
            #pragma unroll
            for (int g = 0; g < 4; ++g)
                in4[g] = *(const float4*)(&scr[g][sb]);    // 4 b128 per c
            #pragma unroll
            for (int hc = 0; hc < 2; ++hc) {
                float4 W0, W1, W2, W3;   // rows di=0..3, cols cg8*8+hc*4..+3
                if (PERM) {
                    const float4* wp = wperm + (size_t)(c * 8 + hc) * 256 + tid;
                    W0 = wp[0 * 256];
                    W1 = wp[2 * 256];
                    W2 = wp[4 * 256];
                    W3 = wp[6 * 256];
                } else {
                    const float* wrow = W_upd +
                        (size_t)(iseg * 16 + c * 4) * DDIM + cg8 * 8 + hc * 4;
                    W0 = *(const float4*)(wrow + 0 * DDIM);
                    W1 = *(const float4*)(wrow + 1 * DDIM);
                    W2 = *(const float4*)(wrow + 2 * DDIM);
                    W3 = *(const float4*)(wrow + 3 * DDIM);
                }
                const f32x2 wA0 = f32x2{W0.x, W0.y}, wB0 = f32x2{W0.z, W0.w};
                const f32x2 wA1 = f32x2{W1.x, W1.y}, wB1 = f32x2{W1.z, W1.w};
                const f32x2 wA2 = f32x2{W2.x, W2.y}, wB2 = f32x2{W2.z, W2.w};
                const f32x2 wA3 = f32x2{W3.x, W3.y}, wB3 = f32x2{W3.z, W3.w};
                #pragma unroll
                for (int g = 0; g < 4; ++g) {
                    const f32x2 ixy = f32x2{in4[g].x, in4[g].y};
                    const f32x2 izw = f32x2{in4[g].z, in4[g].w};
                    f32x2& aA = accP[g * 4 + hc * 2];
                    f32x2& aB = accP[g * 4 + hc * 2 + 1];
                    pk_fma_b<0>(aA, ixy, wA0);   // i = iseg*16 + c*4 + 0
                    pk_fma_b<1>(aA, ixy, wA1);   // i = .. + 1
                    pk_fma_b<0>(aA, izw, wA2);   // i = .. + 2
                    pk_fma_b<1>(aA, izw, wA3);   // i = .. + 3
                    pk_fma_b<0>(aB, ixy, wB0);
                    pk_fma_b<1>(aB, ixy, wB1);
                    pk_fma_b<0>(aB, izw, wB2);
                    pk_fma_b<1>(aB, izw, wB3);
                }
            }
        }
        // packed reduce over iseg lanes (bits 0..3), r14-identical tree
        float q16[16];
        #pragma unroll
        for (int m2 = 0; m2 < 16; ++m2)
            q16[m2] = merge_dpp<0xB1>(accP[m2].x, accP[m2].y, h0);
        float q8[8];
        #pragma unroll
        for (int m2 = 0; m2 < 8; ++m2)
            q8[m2] = merge_dpp<0x4E>(q16[2 * m2], q16[2 * m2 + 1], h1);
        float q4[4];
        #pragma unroll
        for (int m2 = 0; m2 < 4; ++m2) {
            const float lo = q8[2 * m2], hi = q8[2 * m2 + 1];
            const float send = h2 ? lo : hi;
            const float mine = h2 ? hi : lo;
            q4[m2] = mine + __shfl_xor(send, 4);
        }
        float q2[2];
        #pragma unroll
        for (int m2 = 0; m2 < 2; ++m2) {
            const float lo = q4[2 * m2], hi = q4[2 * m2 + 1];
            const float send = h3 ? lo : hi;
            const float mine = h3 ? hi : lo;
            q2[m2] = mine + __shfl_xor(send, 8);
        }
        // epilogue: lane holds j = 16*hgi + (lane&15) = g*8 + colofs
        //   -> g = 2*hgi + ((lane>>3)&1), col = cg8*8 + (lane&7)
        #pragma unroll
        for (int hgi = 0; hgi < 2; ++hgi) {
            const int g = 2 * hgi + ((lane >> 3) & 1);
            const float4 u4 = upd4[g];
            const int ts = __float_as_int(u4.x);
            const float u = q2[hgi] + bu;
            const float addv = (u * u4.y) * u4.z;
            te[g][ts][cg8 * 8 + (lane & 7)] += addv;
        }
        __syncthreads();   // barrier 2: te fully updated

        ag2 = ag2n; gum = gumn; amk = amkn;
    }
}

extern "C" void kernel_launch(void* const* d_in, const int* in_sizes, int n_in,
                              void* d_out, int out_size, void* d_ws, size_t ws_size,
                              hipStream_t stream) {
    const float*         task_embeds  = (const float*)d_in[0];
    const float*         task_nonag   = (const float*)d_in[1];
    const float*         agent_embeds = (const float*)d_in[2];
    const unsigned char* task_mask    = (const unsigned char*)d_in[3];
    const float*         agent_mask   = (const float*)d_in[4];
    const float*         gumbels      = (const float*)d_in[5];
    const float*         W_count      = (const float*)d_in[6];
    const float*         b_count      = (const float*)d_in[7];
    const float*         W_upd        = (const float*)d_in[8];
    const float*         b_upd        = (const float*)d_in[9];
    float* out = (float*)d_out;

    dim3 grid(NBATCH / G);
    dim3 block(NTHREADS);

    if (ws_size >= 2 * DDIM * DDIM * sizeof(float)) {   // 128 KB for wperm
        float4* wp = (float4*)d_ws;
        hipLaunchKernelGGL(wperm_kernel, dim3(32), dim3(256), 0, stream, W_upd, wp);
        hipLaunchKernelGGL(alloc_policy_kernel<true>, grid, block, 0, stream,
                           task_embeds, task_nonag, agent_embeds, task_mask,
                           agent_mask, gumbels, W_count, b_count, W_upd, b_upd,
                           wp, out);
    } else {
        hipLaunchKernelGGL(alloc_policy_kernel<false>, grid, block, 0, stream,
                           task_embeds, task_nonag, agent_embeds, task_mask,
                           agent_mask, gumbels, W_count, b_count, W_upd, b_upd,
                           (const float4*)nullptr, out);
    }
}

// Round 17
// 109.607 us; speedup vs baseline: 2.1250x; 1.2288x over previous
//
#include <hip/hip_runtime.h>
#include <float.h>
#include <math.h>

#define NBATCH   4096
#define NAGENT   16
#define NTASK    16
#define DDIM     128
#define G        8      // batches per block (one per wave)
#define NTHREADS 512    // 8 waves
#define SSEG     20     // scr segment stride (16 data + 4 pad dwords)

typedef float f32x2 __attribute__((ext_vector_type(2)));

// DPP lane permutes (VALU pipe, lane bits 0-3):
//   0xB1 quad_perm xor1, 0x4E quad_perm xor2,
//   0x141 row_half_mirror = xor7, 0x140 row_mirror = xor15
template<int CTRL>
__device__ __forceinline__ float dppf(float x) {
    return __int_as_float(__builtin_amdgcn_update_dpp(
        0, __float_as_int(x), CTRL, 0xF, 0xF, true));
}
template<int CTRL>
__device__ __forceinline__ int dppi(int x) {
    return __builtin_amdgcn_update_dpp(0, x, CTRL, 0xF, 0xF, true);
}

// packed fp32 fma: acc.{lo,hi} += bcast(a.{lo|hi per SEL}) * b.{lo,hi}
// per-component IEEE fma -> bit-identical to two scalar v_fma_f32.
template<int SEL>
__device__ __forceinline__ void pk_fma_b(f32x2& acc, f32x2 a, f32x2 b) {
    if constexpr (SEL == 0)
        asm("v_pk_fma_f32 %0, %1, %2, %0 op_sel:[0,0,0] op_sel_hi:[0,1,1]"
            : "+v"(acc) : "v"(a), "v"(b));
    else
        asm("v_pk_fma_f32 %0, %1, %2, %0 op_sel:[1,0,0] op_sel_hi:[1,1,1]"
            : "+v"(acc) : "v"(a), "v"(b));
}

// 3-op packed merge over a DPP lane-xor level (own-half-first order;
// r13/r14/r15/r16 proven absmax 0.0).
template<int CTRL>
__device__ __forceinline__ float merge_dpp(float lo, float hi, bool h) {
    const float a = lo + dppf<CTRL>(lo);
    const float b = hi + dppf<CTRL>(hi);
    return h ? b : a;
}

// Lane-order permuted W for the 512-thread mapping (iseg=tid&15, cg=tid>>4):
// wp[(c*4+di)*512 + tid] = W_upd[(tid&15)*16 + c*4 + di][(tid>>4)*4 .. +3]
__global__ void wperm_kernel(const float* __restrict__ W_upd,
                             float4* __restrict__ wp) {
    const int q    = blockIdx.x * 256 + threadIdx.x;   // 0..8191
    const int t    = q & 511;
    const int rowc = q >> 9;          // 0..15 = c*4 + di
    const int i    = (t & 15) * 16 + rowc;
    const int col  = (t >> 4) * 4;
    wp[q] = *(const float4*)(W_upd + (size_t)i * DDIM + col);
}

// VGPR-POOL LAW (r2..r16): waves/SIMD = floor(256/VGPR); waves_per_eu MIN
// sets the allocator cap at 256/min. Optimum config (r11/r12/r14, 111.7us):
// 512-thread blocks, min=4 -> 64-reg cap, W streamed from L2 wperm,
// 2 blocks/CU = 16 waves/CU. r16 proved residency > per-wave op count.
// This round: + mirror-DPP softmax (r15/r16-proven) -> -12 DS shfl/step.
template<bool PERM>
__global__ __launch_bounds__(NTHREADS)
__attribute__((amdgpu_waves_per_eu(4, 8)))
void alloc_policy_kernel(const float* __restrict__ task_embeds,
                         const float* __restrict__ task_nonag,
                         const float* __restrict__ agent_embeds,
                         const unsigned char* __restrict__ task_mask,
                         const float* __restrict__ agent_mask,
                         const float* __restrict__ gumbels,
                         const float* __restrict__ W_count,
                         const float* __restrict__ b_count,
                         const float* __restrict__ W_upd,
                         const float* __restrict__ b_upd,
                         const float4* __restrict__ wperm,
                         float* __restrict__ out)
{
    __shared__ __align__(16) float te[G][NTASK][DDIM];     // 64 KB
    __shared__ __align__(16) float scr[G][16 * SSEG];      // 10 KB
    __shared__ __align__(16) float4 sdots4[G][NAGENT];     // 2 KB
    __shared__ __align__(16) float4 upd4[G];

    const int tid  = threadIdx.x;
    const int lane = tid & 63;
    const int w    = tid >> 6;
    const int b0   = blockIdx.x * G;
    const int gb_w = b0 + w;

    const bool h0 = (lane & 1) != 0;
    const bool h1 = (lane & 2) != 0;
    const bool h2 = (lane & 4) != 0;
    const bool h3 = (lane & 8) != 0;

    // phase-M mapping: colgroup cg owns cols cg*4..cg*4+3; iseg owns i in [iseg*16, +16)
    const int cg   = tid >> 4;            // 0..31
    const int iseg = tid & 15;
    const float bu = b_upd[cg * 4 + (tid & 3)];

    const float scalef = sqrtf(128.0f);

    // ---- init te
    {
        const float4* src = (const float4*)(task_embeds + (size_t)b0 * NTASK * DDIM);
        float4* dst = (float4*)(&te[0][0][0]);
        #pragma unroll
        for (int k = 0; k < (G * NTASK * DDIM / 4) / NTHREADS; ++k)  // 8
            dst[k * NTHREADS + tid] = src[k * NTHREADS + tid];
    }

    // ---- init sdots4 per (g,a): s0=dot(ag,Wc0), s1=dot(ag,Wc1), s2=dot(ag,bc)
    {
        const int p = tid >> 2, q = tid & 3;
        const int g = p >> 4,  a = p & 15;
        const float* agp = agent_embeds + ((size_t)(b0 + g) * NAGENT + a) * DDIM + q * 32;
        float a0 = 0.f, a1 = 0.f, a2 = 0.f;
        #pragma unroll
        for (int c = 0; c < 8; ++c) {
            const float4 av = *(const float4*)(agp + c * 4);
            const float4 w0 = *(const float4*)(W_count + q * 32 + c * 4);
            const float4 w1 = *(const float4*)(W_count + DDIM + q * 32 + c * 4);
            const float4 bc = *(const float4*)(b_count + q * 32 + c * 4);
            a0 = fmaf(av.x, w0.x, a0); a0 = fmaf(av.y, w0.y, a0);
            a0 = fmaf(av.z, w0.z, a0); a0 = fmaf(av.w, w0.w, a0);
            a1 = fmaf(av.x, w1.x, a1); a1 = fmaf(av.y, w1.y, a1);
            a1 = fmaf(av.z, w1.z, a1); a1 = fmaf(av.w, w1.w, a1);
            a2 = fmaf(av.x, bc.x, a2); a2 = fmaf(av.y, bc.y, a2);
            a2 = fmaf(av.z, bc.z, a2); a2 = fmaf(av.w, bc.w, a2);
        }
        a0 += __shfl_xor(a0, 1); a0 += __shfl_xor(a0, 2);
        a1 += __shfl_xor(a1, 1); a1 += __shfl_xor(a1, 2);
        a2 += __shfl_xor(a2, 1); a2 += __shfl_xor(a2, 2);
        if (q == 0) sdots4[g][a] = make_float4(a0, a1, a2, 0.f);
    }

    const int tau = lane & 15;
    const float nn_my = task_nonag[gb_w * NTASK + tau];
    const unsigned char mask_my = task_mask[gb_w * NTASK + tau];
    float cc_my = 0.0f;

    const float* agbase = agent_embeds + (size_t)gb_w * NAGENT * DDIM;
    float2 ag2 = *(const float2*)(agbase + lane * 2);                // a=0
    float  gum = gumbels[(size_t)gb_w * NTASK + tau];                // a=0
    float  amk = agent_mask[(size_t)gb_w * NAGENT + 0];

    __syncthreads();

    for (int a = 0; a < NAGENT; ++a) {
        // ================= phase L (wave-private, r14-bit-identical) =========
        float v[16];
        #pragma unroll
        for (int t = 0; t < 16; ++t) {
            const float2 t2 = *(const float2*)(&te[w][t][lane * 2]);
            v[t] = fmaf(ag2.y, t2.y, ag2.x * t2.x);
        }
        float p8[8];
        #pragma unroll
        for (int m2 = 0; m2 < 8; ++m2)
            p8[m2] = merge_dpp<0xB1>(v[2 * m2], v[2 * m2 + 1], h0);
        float p4[4];
        #pragma unroll
        for (int m2 = 0; m2 < 4; ++m2)
            p4[m2] = merge_dpp<0x4E>(p8[2 * m2], p8[2 * m2 + 1], h1);
        float p2v[2];
        #pragma unroll
        for (int m2 = 0; m2 < 2; ++m2) {
            const float lo = p4[2 * m2], hi = p4[2 * m2 + 1];
            const float send = h2 ? lo : hi;
            const float mine = h2 ? hi : lo;
            p2v[m2] = mine + __shfl_xor(send, 4);
        }
        float p1;
        {
            const float lo = p2v[0], hi = p2v[1];
            const float send = h3 ? lo : hi;
            const float mine = h3 ? hi : lo;
            p1 = mine + __shfl_xor(send, 8);
        }
        p1 += __shfl_xor(p1, 16);
        p1 += __shfl_xor(p1, 32);   // all 64 lanes: full dot(ag, te[tau])

        // ========== phase S: softmax/argmax via mirror-DPPs (r15/r16-proven) =
        const float4 sd = sdots4[w][a];
        const float dot_total = p1 + fmaf(nn_my, sd.x, fmaf(cc_my, sd.y, sd.z));
        float z = dot_total / scalef;
        if (mask_my) z = -FLT_MAX;
        z = z + gum;

        float mz = z;
        mz = fmaxf(mz, dppf<0xB1>(mz));
        mz = fmaxf(mz, dppf<0x4E>(mz));
        mz = fmaxf(mz, dppf<0x141>(mz));
        mz = fmaxf(mz, dppf<0x140>(mz));
        const float e = expf(z - mz);
        float ss = e;
        ss += dppf<0xB1>(ss);
        ss += dppf<0x4E>(ss);
        ss += dppf<0x141>(ss);
        ss += dppf<0x140>(ss);
        const float sft = e / ss;

        float mx = sft;
        mx = fmaxf(mx, dppf<0xB1>(mx));
        mx = fmaxf(mx, dppf<0x4E>(mx));
        mx = fmaxf(mx, dppf<0x141>(mx));
        mx = fmaxf(mx, dppf<0x140>(mx));
        int cand = (sft == mx) ? tau : NTASK;
        cand = min(cand, dppi<0xB1>(cand));
        cand = min(cand, dppi<0x4E>(cand));
        cand = min(cand, dppi<0x141>(cand));
        cand = min(cand, dppi<0x140>(cand));
        const int bi = cand;

        const float agm = 1.0f - amk;
        const float onehot = (tau == bi) ? 1.0f : 0.0f;
        const float hh = ((onehot - sft) + sft) * agm;   // exact 0 / exact agm

        if (lane < 16)
            out[((size_t)gb_w * NAGENT + a) * NTASK + tau] = hh;
        cc_my = cc_my + hh * 0.1f;
        if (lane < 16 && tau == bi)
            upd4[w] = make_float4(__int_as_float(bi), hh, agm, 0.f);

        // stage relu(concat(te[bi], ag)) into seg-strided scratch
        {
            const float2 tsel = *(const float2*)(&te[w][bi][lane * 2]);
            float2 r0, r1;
            r0.x = fmaxf(tsel.x, 0.f); r0.y = fmaxf(tsel.y, 0.f);
            r1.x = fmaxf(ag2.x, 0.f);  r1.y = fmaxf(ag2.y, 0.f);
            const int i0 = 2 * lane;
            const int i1 = 128 + 2 * lane;
            *(float2*)(&scr[w][(i0 >> 4) * SSEG + (i0 & 15)]) = r0;
            *(float2*)(&scr[w][(i1 >> 4) * SSEG + (i1 & 15)]) = r1;
        }

        // prefetch next step's globals (latency hidden under phase M)
        const int an = (a + 1) & 15;
        const float2 ag2n = *(const float2*)(agbase + (size_t)an * DDIM + lane * 2);
        const float  gumn = gumbels[((size_t)an * NBATCH + gb_w) * NTASK + tau];
        const float  amkn = agent_mask[(size_t)gb_w * NAGENT + an];

        __syncthreads();   // barrier 1: scr + upd4 published

        // ======== phase M: packed matvec, W streamed coalesced from L2 ======
        f32x2 acc01[G], acc23[G];
        #pragma unroll
        for (int g = 0; g < G; ++g) { acc01[g] = f32x2{0.f, 0.f}; acc23[g] = f32x2{0.f, 0.f}; }
        #pragma unroll
        for (int c = 0; c < 4; ++c) {
            float4 Wc0, Wc1, Wc2, Wc3;   // rows di=0..3 of this chunk, 4 cols each
            if (PERM) {
                const float4* wp = wperm + (size_t)(c * 4) * 512 + tid;
                Wc0 = wp[0 * 512];
                Wc1 = wp[1 * 512];
                Wc2 = wp[2 * 512];
                Wc3 = wp[3 * 512];
            } else {
                const float* wrow = W_upd + (size_t)(iseg * 16 + c * 4) * DDIM + cg * 4;
                Wc0 = *(const float4*)(wrow + 0 * DDIM);
                Wc1 = *(const float4*)(wrow + 1 * DDIM);
                Wc2 = *(const float4*)(wrow + 2 * DDIM);
                Wc3 = *(const float4*)(wrow + 3 * DDIM);
            }
            const f32x2 w01_0 = f32x2{Wc0.x, Wc0.y}, w23_0 = f32x2{Wc0.z, Wc0.w};
            const f32x2 w01_1 = f32x2{Wc1.x, Wc1.y}, w23_1 = f32x2{Wc1.z, Wc1.w};
            const f32x2 w01_2 = f32x2{Wc2.x, Wc2.y}, w23_2 = f32x2{Wc2.z, Wc2.w};
            const f32x2 w01_3 = f32x2{Wc3.x, Wc3.y}, w23_3 = f32x2{Wc3.z, Wc3.w};
            const int sb = iseg * SSEG + c * 4;
            #pragma unroll
            for (int g = 0; g < 8; ++g) {
                const float4 in4 = *(const float4*)(&scr[g][sb]);
                const f32x2 ixy = f32x2{in4.x, in4.y};
                const f32x2 izw = f32x2{in4.z, in4.w};
                pk_fma_b<0>(acc01[g], ixy, w01_0);   // in.x * row di=0
                pk_fma_b<1>(acc01[g], ixy, w01_1);   // in.y * row di=1
                pk_fma_b<0>(acc01[g], izw, w01_2);   // in.z * row di=2
                pk_fma_b<1>(acc01[g], izw, w01_3);   // in.w * row di=3
                pk_fma_b<0>(acc23[g], ixy, w23_0);
                pk_fma_b<1>(acc23[g], ixy, w23_1);
                pk_fma_b<0>(acc23[g], izw, w23_2);
                pk_fma_b<1>(acc23[g], izw, w23_3);
            }
        }
        // packed reduce over iseg lanes (bits 0..3): 32 -> 2 values per lane
        float q16[16];
        #pragma unroll
        for (int m2 = 0; m2 < 16; ++m2) {
            const float lo = (m2 & 1) ? acc23[m2 >> 1].x : acc01[m2 >> 1].x;
            const float hi = (m2 & 1) ? acc23[m2 >> 1].y : acc01[m2 >> 1].y;
            q16[m2] = merge_dpp<0xB1>(lo, hi, h0);
        }
        float q8[8];
        #pragma unroll
        for (int m2 = 0; m2 < 8; ++m2)
            q8[m2] = merge_dpp<0x4E>(q16[2 * m2], q16[2 * m2 + 1], h1);
        float q4[4];
        #pragma unroll
        for (int m2 = 0; m2 < 4; ++m2) {
            const float lo = q8[2 * m2], hi = q8[2 * m2 + 1];
            const float send = h2 ? lo : hi;
            const float mine = h2 ? hi : lo;
            q4[m2] = mine + __shfl_xor(send, 4);
        }
        float q2[2];
        #pragma unroll
        for (int m2 = 0; m2 < 2; ++m2) {
            const float lo = q4[2 * m2], hi = q4[2 * m2 + 1];
            const float send = h3 ? lo : hi;
            const float mine = h3 ? hi : lo;
            q2[m2] = mine + __shfl_xor(send, 8);
        }
        // epilogue: lane handles (g=(lane&15)>>2 + 4*hgi, col cg*4+(lane&3))
        #pragma unroll
        for (int hgi = 0; hgi < 2; ++hgi) {
            const int g = ((lane & 15) >> 2) + hgi * 4;
            const float4 u4 = upd4[g];
            const int ts = __float_as_int(u4.x);
            const float u = q2[hgi] + bu;
            const float addv = (u * u4.y) * u4.z;
            te[g][ts][cg * 4 + (tid & 3)] += addv;
        }
        __syncthreads();   // barrier 2: te fully updated

        ag2 = ag2n; gum = gumn; amk = amkn;
    }
}

extern "C" void kernel_launch(void* const* d_in, const int* in_sizes, int n_in,
                              void* d_out, int out_size, void* d_ws, size_t ws_size,
                              hipStream_t stream) {
    const float*         task_embeds  = (const float*)d_in[0];
    const float*         task_nonag   = (const float*)d_in[1];
    const float*         agent_embeds = (const float*)d_in[2];
    const unsigned char* task_mask    = (const unsigned char*)d_in[3];
    const float*         agent_mask   = (const float*)d_in[4];
    const float*         gumbels      = (const float*)d_in[5];
    const float*         W_count      = (const float*)d_in[6];
    const float*         b_count      = (const float*)d_in[7];
    const float*         W_upd        = (const float*)d_in[8];
    const float*         b_upd        = (const float*)d_in[9];
    float* out = (float*)d_out;

    dim3 grid(NBATCH / G);
    dim3 block(NTHREADS);

    if (ws_size >= 2 * DDIM * DDIM * sizeof(float)) {   // 128 KB for wperm
        float4* wp = (float4*)d_ws;
        hipLaunchKernelGGL(wperm_kernel, dim3(32), dim3(256), 0, stream, W_upd, wp);
        hipLaunchKernelGGL(alloc_policy_kernel<true>, grid, block, 0, stream,
                           task_embeds, task_nonag, agent_embeds, task_mask,
                           agent_mask, gumbels, W_count, b_count, W_upd, b_upd,
                           wp, out);
    } else {
        hipLaunchKernelGGL(alloc_policy_kernel<false>, grid, block, 0, stream,
                           task_embeds, task_nonag, agent_embeds, task_mask,
                           agent_mask, gumbels, W_count, b_count, W_upd, b_upd,
                           (const float4*)nullptr, out);
    }
}